// Round 1
// 342.032 us; speedup vs baseline: 1.1664x; 1.1664x over previous
//
#include <hip/hip_runtime.h>
#include <hip/hip_bf16.h>
#include <stdint.h>

#define B_DIM   8192
#define IN_DIM  4096
#define OUT_DIM 4096
#define BSZ     64
#define NBR_    64
#define BPR_    16
#define KTOT    1024
#define MT      256
#define BKK     32
#define NSTEP   (KTOT / BKK)   // 32

typedef __attribute__((ext_vector_type(4))) float  floatx4;
typedef __attribute__((ext_vector_type(8))) short  shortx8;  // 8 bf16
typedef __attribute__((ext_vector_type(4))) float  fragc;    // 4 fp32 acc

static __device__ __forceinline__ unsigned short f2bf(float f) {
  __bf16 b = (__bf16)f;  // RTNE hardware cvt
  return __builtin_bit_cast(unsigned short, b);
}

__device__ __forceinline__ void gload_lds16(const void* g, void* l) {
  // 16B/lane, LDS dest = wave-uniform base + lane*16
  __builtin_amdgcn_global_load_lds(
      (const __attribute__((address_space(1))) unsigned int*)g,
      (__attribute__((address_space(3))) unsigned int*)l, 16, 0, 0);
}

// ---------------- fused fp32 -> bf16 conversion (x and values) -------------
__global__ __launch_bounds__(256)
void cvt2_kernel(const float* __restrict__ x, const float* __restrict__ v,
                 unsigned short* __restrict__ xb, unsigned short* __restrict__ vb,
                 int xn8, int tn8) {
  const int stride = gridDim.x * blockDim.x;
  for (int i = blockIdx.x * blockDim.x + threadIdx.x; i < tn8; i += stride) {
    const float* src; unsigned short* dst; int idx;
    if (i < xn8) { src = x; dst = xb; idx = i; }
    else         { src = v; dst = vb; idx = i - xn8; }
    floatx4 a = __builtin_nontemporal_load(((const floatx4*)src) + 2 * idx);
    floatx4 b = __builtin_nontemporal_load(((const floatx4*)src) + 2 * idx + 1);
    uint4 o;
    o.x = (unsigned int)f2bf(a.x) | ((unsigned int)f2bf(a.y) << 16);
    o.y = (unsigned int)f2bf(a.z) | ((unsigned int)f2bf(a.w) << 16);
    o.z = (unsigned int)f2bf(b.x) | ((unsigned int)f2bf(b.y) << 16);
    o.w = (unsigned int)f2bf(b.z) | ((unsigned int)f2bf(b.w) << 16);
    ((uint4*)dst)[idx] = o;
  }
}

// ---------------- block-sparse GEMM, 4-buffer LDS + counted vmcnt ----------
// Block = 4 waves, tile 256 rows x 64 cols (one block-row r). Wave = 64x64 via
// 4x4 of 16x16x32 bf16 MFMA. Staging via global_load_lds w=16, 4 LDS buffers
// (3-deep prefetch): steady state keeps 15 loads in flight, waits vmcnt(10)
// (never drains to 0 in the main loop -> ~3 compute phases of latency budget).
// One s_barrier per K-step serves both hazards: (a) own stage(k) complete
// (after per-wave counted vmcnt) across all waves, (b) all waves' ds_reads of
// the buffer stage(k+3) will overwrite are retired (compiler lgkm-waits before
// the MFMAs that consumed them). XOR chunk swizzle kills the 8-way
// ds_read_b128 bank conflict (verified, SQ_LDS_BANK_CONFLICT == 0).
// Grid is 1D, XCD-partitioned: xcd = bid&7 owns a 16r x 16m quadrant-strip,
// walked in 16r x 4m chunks of 64 co-resident blocks (32 CU x 2 blk/CU per
// XCD) -> v slice (2MB) stays L2-resident, x slices fetched once per owner.
__global__ __launch_bounds__(256, 2)
void bsr_gemm(const unsigned short* __restrict__ xb,
              const unsigned short* __restrict__ vb,
              const float* __restrict__ bias, const int* __restrict__ colidx,
              float* __restrict__ out) {
  // XCD-aware decode (bijective over 2048 blocks)
  const int bid    = blockIdx.x;
  const int xcd    = bid & 7;
  const int slot   = bid >> 3;          // 0..255 in dispatch order per XCD
  const int within = slot & 63;         // 64-block co-resident chunk
  const int rloc   = within >> 2;       // 0..15
  const int mloc   = ((slot >> 6) << 2) | (within & 3);  // 0..15
  const int r      = ((xcd & 3) << 4) | rloc;            // block-row 0..63
  const int m0     = ((((xcd >> 2) << 4) | mloc)) * MT;  // batch tile base

  const int tid  = threadIdx.x;
  const int wave = tid >> 6;
  const int lane = tid & 63;
  const int l16  = lane & 15;
  const int quad = lane >> 4;
  const int sub  = lane >> 2;       // staging row within 16-row chunk
  const int slt  = lane & 3;        // staging 16B slot within 64B row
  const int gsw  = slt ^ ((sub >> 1) & 3);   // which global chunk lane stages
  const int csw  = quad ^ ((l16 >> 1) & 3);  // which LDS slot lane reads

  __shared__ __align__(16) unsigned short As0[MT * BKK];
  __shared__ __align__(16) unsigned short As1[MT * BKK];
  __shared__ __align__(16) unsigned short As2[MT * BKK];
  __shared__ __align__(16) unsigned short As3[MT * BKK];
  __shared__ __align__(16) unsigned short Bs0[BSZ * BKK];
  __shared__ __align__(16) unsigned short Bs1[BSZ * BKK];
  __shared__ __align__(16) unsigned short Bs2[BSZ * BKK];
  __shared__ __align__(16) unsigned short Bs3[BSZ * BKK];

  int cidx[BPR_];
  #pragma unroll
  for (int j = 0; j < BPR_; ++j)
    cidx[j] = __builtin_amdgcn_readfirstlane(colidx[r * BPR_ + j]);

  // per-lane staging source bases (shorts)
  const unsigned short* gA =
      xb + (size_t)(m0 + wave * 64 + sub) * IN_DIM + gsw * 8;
  const unsigned short* gB =
      vb + ((size_t)(r * BPR_) * BSZ + wave * 16 + sub) * BSZ + gsw * 8;

  // per-lane LDS read offsets (shorts)
  const int aoff = (wave * 64 + l16) * BKK + csw * 8;
  const int boff = l16 * BKK + csw * 8;

  fragc acc[4][4] = {};

#define STAGE(k, As, Bs)                                                      \
  {                                                                           \
    const int jb_ = (k) >> 1, kb0_ = ((k) & 1) * BKK;                         \
    const int colo_ = cidx[jb_] * BSZ + kb0_;                                 \
    _Pragma("unroll")                                                         \
    for (int i_ = 0; i_ < 4; ++i_)                                            \
      gload_lds16(gA + (size_t)i_ * 16 * IN_DIM + colo_,                      \
                  &As[(wave * 64 + i_ * 16) * BKK]);                          \
    gload_lds16(gB + (size_t)jb_ * BSZ * BSZ + kb0_,                          \
                &Bs[(wave * 16) * BKK]);                                      \
  }

#define COMP(As, Bs)                                                          \
  {                                                                           \
    shortx8 af_[4], bf_[4];                                                   \
    _Pragma("unroll")                                                         \
    for (int mi = 0; mi < 4; ++mi)                                            \
      af_[mi] = *(const shortx8*)&As[aoff + mi * 16 * BKK];                   \
    _Pragma("unroll")                                                         \
    for (int ni = 0; ni < 4; ++ni)                                            \
      bf_[ni] = *(const shortx8*)&Bs[boff + ni * 16 * BKK];                   \
    _Pragma("unroll")                                                         \
    for (int mi = 0; mi < 4; ++mi) {                                          \
      _Pragma("unroll")                                                       \
      for (int ni = 0; ni < 4; ++ni)                                          \
        acc[mi][ni] = __builtin_amdgcn_mfma_f32_16x16x32_bf16(                \
            af_[mi], bf_[ni], acc[mi][ni], 0, 0, 0);                          \
    }                                                                         \
  }

  // steady state: stages k, k+1, k+2 in flight (15 loads). Wait for the
  // oldest 5 (stage k) -> vmcnt(10); tail decreases 10 -> 5 -> 0. k is a
  // compile-time constant after full unroll, so the branches fold away.
#define ITER(k, Ac, Bc, An, Bn)                                              \
  do {                                                                       \
    if ((k) < NSTEP - 2)                                                     \
      asm volatile("s_waitcnt vmcnt(10)" ::: "memory");                      \
    else if ((k) == NSTEP - 2)                                               \
      asm volatile("s_waitcnt vmcnt(5)" ::: "memory");                       \
    else                                                                     \
      asm volatile("s_waitcnt vmcnt(0)" ::: "memory");                       \
    __builtin_amdgcn_s_barrier();                                            \
    asm volatile("" ::: "memory");                                           \
    if ((k) + 3 < NSTEP) { STAGE((k) + 3, An, Bn); }                         \
    COMP(Ac, Bc);                                                            \
  } while (0)

  STAGE(0, As0, Bs0);
  STAGE(1, As1, Bs1);
  STAGE(2, As2, Bs2);

  #pragma unroll
  for (int k = 0; k < NSTEP; k += 4) {
    ITER(k + 0, As0, Bs0, As3, Bs3);
    ITER(k + 1, As1, Bs1, As0, Bs0);
    ITER(k + 2, As2, Bs2, As1, Bs1);
    ITER(k + 3, As3, Bs3, As2, Bs2);
  }
#undef STAGE
#undef COMP
#undef ITER

  // epilogue: C/D layout col=lane&15, row=quad*4+reg (verified)
  #pragma unroll
  for (int ni = 0; ni < 4; ++ni) {
    const int col = r * BSZ + ni * 16 + l16;
    const float bv = bias[col];
    #pragma unroll
    for (int mi = 0; mi < 4; ++mi) {
      #pragma unroll
      for (int reg = 0; reg < 4; ++reg) {
        const int row = m0 + wave * 64 + mi * 16 + quad * 4 + reg;
        out[(size_t)row * OUT_DIM + col] = acc[mi][ni][reg] + bv;
      }
    }
  }
}

// ---------------- correctness-only fallback (no workspace) -----------------
__global__ __launch_bounds__(256)
void bsr_naive(const float* __restrict__ x, const float* __restrict__ v,
               const float* __restrict__ bias, const int* __restrict__ colidx,
               float* __restrict__ out) {
  const size_t gid = (size_t)blockIdx.x * blockDim.x + threadIdx.x;
  if (gid >= (size_t)B_DIM * OUT_DIM) return;
  const int b = gid / OUT_DIM;
  const int oc = gid % OUT_DIM;
  const int rr = oc / BSZ, o = oc % BSZ;
  float s = bias[oc];
  for (int j = 0; j < BPR_; ++j) {
    const int c = colidx[rr * BPR_ + j];
    const float* xp = x + (size_t)b * IN_DIM + c * BSZ;
    const float* vp = v + ((size_t)(rr * BPR_ + j) * BSZ + o) * BSZ;
    for (int k = 0; k < BSZ; ++k) s += vp[k] * xp[k];
  }
  out[gid] = s;
}

extern "C" void kernel_launch(void* const* d_in, const int* in_sizes, int n_in,
                              void* d_out, int out_size, void* d_ws, size_t ws_size,
                              hipStream_t stream) {
  const float* x    = (const float*)d_in[0];
  const float* vals = (const float*)d_in[1];
  const float* bias = (const float*)d_in[2];
  const int*   cols = (const int*)d_in[3];
  float* out = (float*)d_out;

  const size_t x_elems = (size_t)B_DIM * IN_DIM;
  const size_t v_elems = (size_t)NBR_ * BPR_ * BSZ * BSZ;
  const size_t xb_bytes = x_elems * sizeof(unsigned short);
  const size_t vb_bytes = v_elems * sizeof(unsigned short);

  if (ws_size >= xb_bytes + vb_bytes) {
    unsigned short* xbp = (unsigned short*)d_ws;
    unsigned short* vbp = (unsigned short*)((char*)d_ws + xb_bytes);
    const int xn8 = (int)(x_elems / 8);
    const int tn8 = (int)((x_elems + v_elems) / 8);
    cvt2_kernel<<<dim3(9216), dim3(256), 0, stream>>>(x, vals, xbp, vbp, xn8, tn8);
    bsr_gemm<<<dim3(NBR_ * (B_DIM / MT)), dim3(256), 0, stream>>>(
        xbp, vbp, bias, cols, out);
  } else {
    const size_t n = (size_t)B_DIM * OUT_DIM;
    bsr_naive<<<dim3((unsigned)((n + 255) / 256)), dim3(256), 0, stream>>>(
        x, vals, bias, cols, out);
  }
}

// Round 4
// 338.318 us; speedup vs baseline: 1.1792x; 1.0110x over previous
//
#include <hip/hip_runtime.h>
#include <hip/hip_bf16.h>
#include <stdint.h>

#define B_DIM   8192
#define IN_DIM  4096
#define OUT_DIM 4096
#define BSZ     64
#define NBR_    64
#define BPR_    16
#define KTOT    1024
#define MT      256
#define BKK     32
#define NSTEP   (KTOT / BKK)   // 32

typedef __attribute__((ext_vector_type(4))) float  floatx4;
typedef __attribute__((ext_vector_type(8))) short  shortx8;  // 8 bf16
typedef __attribute__((ext_vector_type(4))) float  fragc;    // 4 fp32 acc

static __device__ __forceinline__ unsigned short f2bf(float f) {
  __bf16 b = (__bf16)f;  // RTNE hardware cvt
  return __builtin_bit_cast(unsigned short, b);
}

__device__ __forceinline__ void gload_lds16(const void* g, void* l) {
  // 16B/lane, LDS dest = wave-uniform base + lane*16
  __builtin_amdgcn_global_load_lds(
      (const __attribute__((address_space(1))) unsigned int*)g,
      (__attribute__((address_space(3))) unsigned int*)l, 16, 0, 0);
}

// ---------------- fused fp32 -> bf16 conversion (x and values) -------------
// Plain (cached) loads: nontemporal hint removed to test whether it was the
// source of this kernel's anomalously low effective bandwidth.
__global__ __launch_bounds__(256)
void cvt2_kernel(const float* __restrict__ x, const float* __restrict__ v,
                 unsigned short* __restrict__ xb, unsigned short* __restrict__ vb,
                 int xn8, int tn8) {
  const int stride = gridDim.x * blockDim.x;
  for (int i = blockIdx.x * blockDim.x + threadIdx.x; i < tn8; i += stride) {
    const float* src; unsigned short* dst; int idx;
    if (i < xn8) { src = x; dst = xb; idx = i; }
    else         { src = v; dst = vb; idx = i - xn8; }
    floatx4 a = ((const floatx4*)src)[2 * idx];
    floatx4 b = ((const floatx4*)src)[2 * idx + 1];
    uint4 o;
    o.x = (unsigned int)f2bf(a.x) | ((unsigned int)f2bf(a.y) << 16);
    o.y = (unsigned int)f2bf(a.z) | ((unsigned int)f2bf(a.w) << 16);
    o.z = (unsigned int)f2bf(b.x) | ((unsigned int)f2bf(b.y) << 16);
    o.w = (unsigned int)f2bf(b.z) | ((unsigned int)f2bf(b.w) << 16);
    ((uint4*)dst)[idx] = o;
  }
}

// ---------------- block-sparse GEMM, 4-buffer LDS + counted vmcnt ----------
// VERIFIED round-1 core (passed, 126us, SQ_LDS_BANK_CONFLICT==0), unchanged
// except the bid->(r,m) decode. Block = 4 waves, tile 256x64. Staging via
// global_load_lds w=16, 4 LDS buffers, 3-deep prefetch, steady-state
// vmcnt(10) (never drains to 0 in the main loop). One s_barrier per K-step.
// XOR chunk swizzle kills the 8-way ds_read_b128 bank conflict.
//
// NEW decode: XCD (bid&7) owns m-tiles [xcd*4, xcd*4+4) x ALL 64 r.
// slot = bid>>3 walks r fastest: the XCD's 64 co-resident blocks (32CU x
// 2blk/CU) are exactly one (m-tile x all-r) phase -> the 2MB xb tile is
// L2-resident for the phase and each m-tile is fetched from HBM by exactly
// one XCD (was 4 in round 1 -> FETCH 264MB). vb re-reads stream from L3.
__global__ __launch_bounds__(256, 2)
void bsr_gemm(const unsigned short* __restrict__ xb,
              const unsigned short* __restrict__ vb,
              const float* __restrict__ bias, const int* __restrict__ colidx,
              float* __restrict__ out) {
  const int bid  = blockIdx.x;
  const int xcd  = bid & 7;
  const int slot = bid >> 3;            // 0..255 in dispatch order per XCD
  const int r    = slot & 63;           // block-row 0..63 (fastest)
  const int mt   = xcd * 4 + (slot >> 6);  // m-tile 0..31, 4 per XCD
  const int m0   = mt * MT;

  const int tid  = threadIdx.x;
  const int wave = tid >> 6;
  const int lane = tid & 63;
  const int l16  = lane & 15;
  const int quad = lane >> 4;
  const int sub  = lane >> 2;       // staging row within 16-row chunk
  const int slt  = lane & 3;        // staging 16B slot within 64B row
  const int gsw  = slt ^ ((sub >> 1) & 3);   // which global chunk lane stages
  const int csw  = quad ^ ((l16 >> 1) & 3);  // which LDS slot lane reads

  __shared__ __align__(16) unsigned short As0[MT * BKK];
  __shared__ __align__(16) unsigned short As1[MT * BKK];
  __shared__ __align__(16) unsigned short As2[MT * BKK];
  __shared__ __align__(16) unsigned short As3[MT * BKK];
  __shared__ __align__(16) unsigned short Bs0[BSZ * BKK];
  __shared__ __align__(16) unsigned short Bs1[BSZ * BKK];
  __shared__ __align__(16) unsigned short Bs2[BSZ * BKK];
  __shared__ __align__(16) unsigned short Bs3[BSZ * BKK];

  int cidx[BPR_];
  #pragma unroll
  for (int j = 0; j < BPR_; ++j)
    cidx[j] = __builtin_amdgcn_readfirstlane(colidx[r * BPR_ + j]);

  // per-lane staging source bases (shorts)
  const unsigned short* gA =
      xb + (size_t)(m0 + wave * 64 + sub) * IN_DIM + gsw * 8;
  const unsigned short* gB =
      vb + ((size_t)(r * BPR_) * BSZ + wave * 16 + sub) * BSZ + gsw * 8;

  // per-lane LDS read offsets (shorts)
  const int aoff = (wave * 64 + l16) * BKK + csw * 8;
  const int boff = l16 * BKK + csw * 8;

  fragc acc[4][4] = {};

#define STAGE(k, As, Bs)                                                      \
  {                                                                           \
    const int jb_ = (k) >> 1, kb0_ = ((k) & 1) * BKK;                         \
    const int colo_ = cidx[jb_] * BSZ + kb0_;                                 \
    _Pragma("unroll")                                                         \
    for (int i_ = 0; i_ < 4; ++i_)                                            \
      gload_lds16(gA + (size_t)i_ * 16 * IN_DIM + colo_,                      \
                  &As[(wave * 64 + i_ * 16) * BKK]);                          \
    gload_lds16(gB + (size_t)jb_ * BSZ * BSZ + kb0_,                          \
                &Bs[(wave * 16) * BKK]);                                      \
  }

#define COMP(As, Bs)                                                          \
  {                                                                           \
    shortx8 af_[4], bf_[4];                                                   \
    _Pragma("unroll")                                                         \
    for (int mi = 0; mi < 4; ++mi)                                            \
      af_[mi] = *(const shortx8*)&As[aoff + mi * 16 * BKK];                   \
    _Pragma("unroll")                                                         \
    for (int ni = 0; ni < 4; ++ni)                                            \
      bf_[ni] = *(const shortx8*)&Bs[boff + ni * 16 * BKK];                   \
    _Pragma("unroll")                                                         \
    for (int mi = 0; mi < 4; ++mi) {                                          \
      _Pragma("unroll")                                                       \
      for (int ni = 0; ni < 4; ++ni)                                          \
        acc[mi][ni] = __builtin_amdgcn_mfma_f32_16x16x32_bf16(                \
            af_[mi], bf_[ni], acc[mi][ni], 0, 0, 0);                          \
    }                                                                         \
  }

  // steady state: stages k, k+1, k+2 in flight (15 loads). Wait for the
  // oldest 5 (stage k) -> vmcnt(10); tail decreases 10 -> 5 -> 0. k is a
  // compile-time constant after full unroll, so the branches fold away.
#define ITER(k, Ac, Bc, An, Bn)                                              \
  do {                                                                       \
    if ((k) < NSTEP - 2)                                                     \
      asm volatile("s_waitcnt vmcnt(10)" ::: "memory");                      \
    else if ((k) == NSTEP - 2)                                               \
      asm volatile("s_waitcnt vmcnt(5)" ::: "memory");                       \
    else                                                                     \
      asm volatile("s_waitcnt vmcnt(0)" ::: "memory");                       \
    __builtin_amdgcn_s_barrier();                                            \
    asm volatile("" ::: "memory");                                           \
    if ((k) + 3 < NSTEP) { STAGE((k) + 3, An, Bn); }                         \
    COMP(Ac, Bc);                                                            \
  } while (0)

  STAGE(0, As0, Bs0);
  STAGE(1, As1, Bs1);
  STAGE(2, As2, Bs2);

  #pragma unroll
  for (int k = 0; k < NSTEP; k += 4) {
    ITER(k + 0, As0, Bs0, As3, Bs3);
    ITER(k + 1, As1, Bs1, As0, Bs0);
    ITER(k + 2, As2, Bs2, As1, Bs1);
    ITER(k + 3, As3, Bs3, As2, Bs2);
  }
#undef STAGE
#undef COMP
#undef ITER

  // epilogue: C/D layout col=lane&15, row=quad*4+reg (verified)
  #pragma unroll
  for (int ni = 0; ni < 4; ++ni) {
    const int col = r * BSZ + ni * 16 + l16;
    const float bv = bias[col];
    #pragma unroll
    for (int mi = 0; mi < 4; ++mi) {
      #pragma unroll
      for (int reg = 0; reg < 4; ++reg) {
        const int row = m0 + wave * 64 + mi * 16 + quad * 4 + reg;
        out[(size_t)row * OUT_DIM + col] = acc[mi][ni][reg] + bv;
      }
    }
  }
}

// ---------------- correctness-only fallback (no workspace) -----------------
__global__ __launch_bounds__(256)
void bsr_naive(const float* __restrict__ x, const float* __restrict__ v,
               const float* __restrict__ bias, const int* __restrict__ colidx,
               float* __restrict__ out) {
  const size_t gid = (size_t)blockIdx.x * blockDim.x + threadIdx.x;
  if (gid >= (size_t)B_DIM * OUT_DIM) return;
  const int b = gid / OUT_DIM;
  const int oc = gid % OUT_DIM;
  const int rr = oc / BSZ, o = oc % BSZ;
  float s = bias[oc];
  for (int j = 0; j < BPR_; ++j) {
    const int c = colidx[rr * BPR_ + j];
    const float* xp = x + (size_t)b * IN_DIM + c * BSZ;
    const float* vp = v + ((size_t)(rr * BPR_ + j) * BSZ + o) * BSZ;
    for (int k = 0; k < BSZ; ++k) s += vp[k] * xp[k];
  }
  out[gid] = s;
}

extern "C" void kernel_launch(void* const* d_in, const int* in_sizes, int n_in,
                              void* d_out, int out_size, void* d_ws, size_t ws_size,
                              hipStream_t stream) {
  const float* x    = (const float*)d_in[0];
  const float* vals = (const float*)d_in[1];
  const float* bias = (const float*)d_in[2];
  const int*   cols = (const int*)d_in[3];
  float* out = (float*)d_out;

  const size_t x_elems = (size_t)B_DIM * IN_DIM;
  const size_t v_elems = (size_t)NBR_ * BPR_ * BSZ * BSZ;
  const size_t xb_bytes = x_elems * sizeof(unsigned short);
  const size_t vb_bytes = v_elems * sizeof(unsigned short);

  if (ws_size >= xb_bytes + vb_bytes) {
    unsigned short* xbp = (unsigned short*)d_ws;
    unsigned short* vbp = (unsigned short*)((char*)d_ws + xb_bytes);
    const int xn8 = (int)(x_elems / 8);
    const int tn8 = (int)((x_elems + v_elems) / 8);
    cvt2_kernel<<<dim3(9216), dim3(256), 0, stream>>>(x, vals, xbp, vbp, xn8, tn8);
    bsr_gemm<<<dim3(NBR_ * (B_DIM / MT)), dim3(256), 0, stream>>>(
        xbp, vbp, bias, cols, out);
  } else {
    const size_t n = (size_t)B_DIM * OUT_DIM;
    bsr_naive<<<dim3((unsigned)((n + 255) / 256)), dim3(256), 0, stream>>>(
        x, vals, bias, cols, out);
  }
}